// Round 1
// 721.821 us; speedup vs baseline: 1.0721x; 1.0721x over previous
//
#include <hip/hip_runtime.h>
#include <math.h>

#define HORIZON 15
#define PAD 7
#define CIN 48
#define C2 12
#define LAT 6
#define EPS 1e-5f
#define NREP 16

typedef __bf16 bf16x8 __attribute__((ext_vector_type(8)));
typedef float f32x4 __attribute__((ext_vector_type(4)));
typedef unsigned short ushort8v __attribute__((ext_vector_type(8)));
typedef unsigned short ushortT;

// bf16 split: v ~= hi + lo with hi = bf16(v), lo = bf16(v - hi)
__device__ inline void bfsplit(float v, ushortT& h, ushortT& l) {
    __bf16 bh = (__bf16)v;
    float fh = (float)bh;
    __bf16 bl = (__bf16)(v - fh);
    h = __builtin_bit_cast(ushortT, bh);
    l = __builtin_bit_cast(ushortT, bl);
}

// ---------------------------------------------------------------------------
// prep: dense banded split weight matrices (n-major, k-contiguous, padded),
// w3t for tail, rfft trig table.
// W1: [768][736]  n = l*48+co (<720), k = ci*15+t (<720)
// W2: [192][736]  n = l*12+co (<180), k = t*48+ci (<720)
// ---------------------------------------------------------------------------
__global__ void prep_kernel(const float* __restrict__ w1, const float* __restrict__ w2,
                            const float* __restrict__ w3,
                            ushortT* __restrict__ w1h, ushortT* __restrict__ w1l,
                            ushortT* __restrict__ w2h, ushortT* __restrict__ w2l,
                            float* __restrict__ w3t, float* __restrict__ trig) {
    int idx = blockIdx.x * blockDim.x + threadIdx.x;
    const int n1 = 768 * 736;
    const int n2 = 192 * 736;
    const int n3 = C2 * HORIZON * LAT;
    if (idx < n1) {
        int n = idx / 736, k = idx % 736;
        float v = 0.f;
        if (n < 720 && k < 720) {
            int l = n / 48, co = n % 48, ci = k / 15, t = k % 15;
            int d = t - l;
            if (d >= -PAD && d <= PAD) v = w1[(co * CIN + ci) * HORIZON + (d + PAD)];
        }
        ushortT h, lo; bfsplit(v, h, lo);
        w1h[idx] = h; w1l[idx] = lo;
    } else if (idx < n1 + n2) {
        int j = idx - n1;
        int n = j / 736, k = j % 736;
        float v = 0.f;
        if (n < 180 && k < 720) {
            int l = n / 12, co = n % 12, t = k / 48, ci = k % 48;
            int d = t - l;
            if (d >= -PAD && d <= PAD) v = w2[(co * CIN + ci) * HORIZON + (d + PAD)];
        }
        ushortT h, lo; bfsplit(v, h, lo);
        w2h[j] = h; w2l[j] = lo;
    } else if (idx < n1 + n2 + n3) {
        int j = idx - n1 - n2;
        int co = j % LAT; int r = j / LAT; int k = r % HORIZON; int ci = r / HORIZON;
        w3t[j] = w3[(co * C2 + ci) * HORIZON + k];
    } else if (idx < n1 + n2 + n3 + 7 * HORIZON) {
        int j = idx - (n1 + n2 + n3);
        int l = j % HORIZON; int f = j / HORIZON + 1;
        double ang = -2.0 * 3.14159265358979323846 * (double)(f * l) / 15.0;
        trig[j * 2]     = (float)cos(ang);
        trig[j * 2 + 1] = (float)sin(ang);
    }
}

// ---------------------------------------------------------------------------
// Split-precision bf16 MFMA GEMM, pipelined:
//   acc = Ah*Bh + Al*Bh + Ah*Bl  (fp32-fidelity; identical op order to the
//   previous version -> bit-identical results)
//
// Pipeline (the round-0 kernel was stall-bound: busiest pipe (LDS) at 38%,
// per-SIMD MFMA ~8%; the 2x __syncthreads per K-step each forced a full
// vmcnt(0) drain):
//   * A fragments built directly in registers (the old LDS round-trip for A
//     was write/read of identical addresses by the same wave) -> -16KB LDS,
//     -8 ds-ops/wave/step.
//   * B staged by global_load_lds (wave-uniform dst base + lane*16B, exactly
//     our layout) into a DOUBLE-buffered LDS tile.
//   * One stage of {8 DMA + 4 A-float4} issued per K-step for step k+1;
//     s_waitcnt vmcnt(NVM) leaves them in flight while guaranteeing step k's
//     stage is complete. Raw s_barrier (no implicit drain). Never vmcnt(0)
//     in the main loop.
//   * For FUSE_BN, bnp lives in LDS so the BN loads never enter the vmcnt
//     FIFO (a global bnp load would force a drain at its use). The 8
//     channels per fragment are consecutive mod 48 (k = 0 mod 8 -> no wrap),
//     read as 4x ds_read_b128.
// Stats layout PLANAR: s_stats[c] = sum, s_stats[CSTAT+c] = sumsq.
// ---------------------------------------------------------------------------
#define SBAR() asm volatile("s_barrier" ::: "memory")
#define GLDS16(SRC, DST)                                                      \
    __builtin_amdgcn_global_load_lds(                                         \
        (const __attribute__((address_space(1))) void*)(SRC),                 \
        (__attribute__((address_space(3))) void*)(DST), 16, 0, 0)

template <int NFRAG, int CSTAT, bool FUSE_BN>
__global__ __launch_bounds__(256, 2)
void gemm_split(const float* __restrict__ A, int Ka,
                const ushortT* __restrict__ Bh, const ushortT* __restrict__ Bl,
                const float* __restrict__ bnp,
                float* __restrict__ Y, int ldy, int nreal,
                float* __restrict__ stats) {
    constexpr int NB  = (NFRAG == 15) ? 16 : 12;   // staged 16-col n-blocks
    constexpr int NBW = NB / 4;                    // n-blocks per wave
    constexpr int NVM = NBW * 2 + 4;               // vmem ops per pipeline stage

    __shared__ __attribute__((aligned(16))) ushortT s_bh[2][NB * 512];
    __shared__ __attribute__((aligned(16))) ushortT s_bl[2][NB * 512];
    __shared__ float s_stats[2 * CSTAT];
    __shared__ float s_bnp[96];

    const int tid = threadIdx.x;
    const int w = tid >> 6, lane = tid & 63;
    const int lr = lane & 15, lq = lane >> 4;
    if (tid < 2 * CSTAT) s_stats[tid] = 0.f;
    if (FUSE_BN && tid < 96) s_bnp[tid] = bnp[tid];
    __syncthreads();

    // grid: x = column-group (adjacent dispatch -> shared A slab hits L2),
    //       y = row-block
    const long m_base = (long)blockIdx.y * 128;
    const int n0 = blockIdx.x * (NFRAG * 16);

    // per-lane global source bases
    const float* arow0 = A + (m_base + w * 32 + lr) * (long)Ka;
    const float* arow1 = arow0 + 16 * (long)Ka;
    const long bdelta = Bl - Bh;
    const ushortT* bsrc[NBW];
#pragma unroll
    for (int j = 0; j < NBW; j++)
        bsrc[j] = Bh + (long)(n0 + (w * NBW + j) * 16 + lr) * 736 + lq * 8;

    f32x4 acc[2][NFRAG];
#pragma unroll
    for (int i = 0; i < 2; i++)
#pragma unroll
        for (int jf = 0; jf < NFRAG; jf++) acc[i][jf] = (f32x4){0.f, 0.f, 0.f, 0.f};

    float4 pfA[4], pfB[4];
    bf16x8 ah[2], al[2];

// stage step KS: 2*NBW DMA loads into B buffer BUF + 4 A float4 loads into PF.
// A guard never has exec==0 (lq=0 lanes always in-bounds), so the vmem-op
// count per stage is exactly NVM for every wave at every step.
#define ISSUE_STEP(KS, BUF, PF)                                               \
    do {                                                                      \
        const int k0_ = (KS) * 32;                                            \
        _Pragma("unroll")                                                     \
        for (int j_ = 0; j_ < NBW; j_++) {                                    \
            const ushortT* g_ = bsrc[j_] + k0_;                               \
            GLDS16(g_, &s_bh[BUF][(w * NBW + j_) * 512]);                     \
            GLDS16(g_ + bdelta, &s_bl[BUF][(w * NBW + j_) * 512]);            \
        }                                                                     \
        const int ka_ = k0_ + lq * 8;                                         \
        _Pragma("unroll")                                                     \
        for (int fr_ = 0; fr_ < 2; fr_++) {                                   \
            float4 z_ = make_float4(0.f, 0.f, 0.f, 0.f);                      \
            PF[fr_ * 2] = z_; PF[fr_ * 2 + 1] = z_;                           \
            if (ka_ < Ka) {                                                   \
                const float4* p_ =                                            \
                    (const float4*)((fr_ ? arow1 : arow0) + ka_);             \
                PF[fr_ * 2] = p_[0]; PF[fr_ * 2 + 1] = p_[1];                 \
            }                                                                 \
        }                                                                     \
    } while (0)

// (optional BN+ELU) + bf16 split of PF -> ah/al fragments
#define SPLIT_STEP(PF, KS)                                                    \
    do {                                                                      \
        const int kb_ = (KS) * 32 + lq * 8;                                   \
        float4 qq_[4];                                                        \
        if (FUSE_BN) {                                                        \
            const int cb_ = (kb_ % 48) * 2;  /* no wrap across 8 elems */     \
            _Pragma("unroll")                                                 \
            for (int m_ = 0; m_ < 4; m_++)                                    \
                qq_[m_] = *(const float4*)(&s_bnp[cb_ + m_ * 4]);             \
        }                                                                     \
        _Pragma("unroll")                                                     \
        for (int fr_ = 0; fr_ < 2; fr_++) {                                   \
            float f_[8] = {PF[fr_*2].x,   PF[fr_*2].y,                        \
                           PF[fr_*2].z,   PF[fr_*2].w,                        \
                           PF[fr_*2+1].x, PF[fr_*2+1].y,                      \
                           PF[fr_*2+1].z, PF[fr_*2+1].w};                     \
            ushort8v uh_, ul_;                                                \
            _Pragma("unroll")                                                 \
            for (int jj = 0; jj < 8; jj++) {                                  \
                float v_ = f_[jj];                                            \
                if (FUSE_BN) {                                                \
                    float sc_ = (jj & 1) ? qq_[jj >> 1].z : qq_[jj >> 1].x;   \
                    float sh_ = (jj & 1) ? qq_[jj >> 1].w : qq_[jj >> 1].y;   \
                    float h_ = fmaf(v_, sc_, sh_);                            \
                    v_ = h_ > 0.f ? h_ : expm1f(h_);                          \
                }                                                             \
                ushortT hh_, ll_; bfsplit(v_, hh_, ll_);                      \
                uh_[jj] = hh_; ul_[jj] = ll_;                                 \
            }                                                                 \
            ah[fr_] = __builtin_bit_cast(bf16x8, uh_);                        \
            al[fr_] = __builtin_bit_cast(bf16x8, ul_);                        \
        }                                                                     \
    } while (0)

#define COMPUTE_STEP(BUF)                                                     \
    do {                                                                      \
        __builtin_amdgcn_s_setprio(1);                                        \
        _Pragma("unroll")                                                     \
        for (int fc = 0; fc < NFRAG; fc++) {                                  \
            bf16x8 bhf = *(const bf16x8*)(&s_bh[BUF][fc * 512 + lane * 8]);   \
            bf16x8 blf = *(const bf16x8*)(&s_bl[BUF][fc * 512 + lane * 8]);   \
            _Pragma("unroll")                                                 \
            for (int fr = 0; fr < 2; fr++) {                                  \
                acc[fr][fc] = __builtin_amdgcn_mfma_f32_16x16x32_bf16(        \
                    ah[fr], bhf, acc[fr][fc], 0, 0, 0);                       \
                acc[fr][fc] = __builtin_amdgcn_mfma_f32_16x16x32_bf16(        \
                    al[fr], bhf, acc[fr][fc], 0, 0, 0);                       \
                acc[fr][fc] = __builtin_amdgcn_mfma_f32_16x16x32_bf16(        \
                    ah[fr], blf, acc[fr][fc], 0, 0, 0);                       \
            }                                                                 \
        }                                                                     \
        __builtin_amdgcn_s_setprio(0);                                        \
    } while (0)

#define WAITP() asm volatile("s_waitcnt vmcnt(%0)" ::"n"(NVM) : "memory")

    // KSTEPS = 23 (odd; tail step uses buffer 0). Ping-pong of pf/buf is
    // fully static via 2x manual unroll (runtime-indexed pf -> scratch).
    ISSUE_STEP(0, 0, pfA);
#pragma unroll 1
    for (int k2 = 0; k2 + 2 < 23; k2 += 2) {
        ISSUE_STEP(k2 + 1, 1, pfB);
        WAITP();                 // step k2 resident; step k2+1 still in flight
        SBAR();
        SPLIT_STEP(pfA, k2);
        COMPUTE_STEP(0);
        SBAR();                  // buf0 reads done -> next DMA may overwrite
        ISSUE_STEP(k2 + 2, 0, pfA);
        WAITP();
        SBAR();
        SPLIT_STEP(pfB, k2 + 1);
        COMPUTE_STEP(1);
        SBAR();
    }
    asm volatile("s_waitcnt vmcnt(0)" ::: "memory");
    SBAR();
    SPLIT_STEP(pfA, 22);
    COMPUTE_STEP(0);

#undef ISSUE_STEP
#undef SPLIT_STEP
#undef COMPUTE_STEP
#undef WAITP

    // ---- epilogue: store + per-channel stats (PLANAR layout) ----
    // C/D layout: col = lane&15, row = (lane>>4)*4 + reg
    float ps[3] = {0.f, 0.f, 0.f}, qs[3] = {0.f, 0.f, 0.f};
#pragma unroll
    for (int fc = 0; fc < NFRAG; fc++) {
        int col = n0 + fc * 16 + lr;
        int j = fc % 3;
#pragma unroll
        for (int fr = 0; fr < 2; fr++) {
#pragma unroll
            for (int r = 0; r < 4; r++) {
                float v = acc[fr][fc][r];
                long row = m_base + w * 32 + fr * 16 + lq * 4 + r;
                if (col < nreal) Y[row * (long)ldy + col] = v;
                ps[j] += v;
                qs[j] = fmaf(v, v, qs[j]);
            }
        }
    }
#pragma unroll
    for (int j = 0; j < 3; j++) {
        int c = (lr + 16 * j) % CSTAT;
        atomicAdd(&s_stats[c], ps[j]);
        atomicAdd(&s_stats[CSTAT + c], qs[j]);
    }
    __syncthreads();
    if (tid < 2 * CSTAT)
        atomicAdd(&stats[(blockIdx.y & (NREP - 1)) * 2 * CSTAT + tid], s_stats[tid]);
}

// ---------------------------------------------------------------------------
// finalize BN: planar stats [sum[0..C-1], sumsq[0..C-1]] per replica
// ---------------------------------------------------------------------------
__global__ void finalize_bn(const float* __restrict__ stats, const float* __restrict__ g,
                            const float* __restrict__ be, float* __restrict__ bn,
                            int C, float invN) {
    int c = threadIdx.x;
    if (c >= C) return;
    float s1 = 0.f, s2 = 0.f;
    for (int r = 0; r < NREP; r++) { s1 += stats[r * 2 * C + c]; s2 += stats[r * 2 * C + C + c]; }
    float m   = s1 * invN;
    float var = s2 * invN - m * m;
    float sc  = g[c] * rsqrtf(var + EPS);
    bn[c * 2]     = sc;
    bn[c * 2 + 1] = fmaf(-m, sc, be[c]);
}

// ---------------------------------------------------------------------------
// tail: BN2+ELU fused on load -> conv3 (+b3) -> rfft stats + phase linear
// ---------------------------------------------------------------------------
__global__ __launch_bounds__(256) void tail_kernel(const float* __restrict__ h2,
                                                   const float* __restrict__ w3t,
                                                   const float* __restrict__ b3,
                                                   const float* __restrict__ pw,
                                                   const float* __restrict__ trig,
                                                   const float* __restrict__ bn2,
                                                   float* __restrict__ out,
                                                   float* __restrict__ vout,
                                                   float* __restrict__ stats) {
    __shared__ float s_sum[2 * LAT];
    __shared__ float s_sq[2 * LAT];
    int t = threadIdx.x;
    if (t < 2 * LAT) { s_sum[t] = 0.f; s_sq[t] = 0.f; }
    __syncthreads();

    int id = blockIdx.x * 256 + t;
    int co = id % LAT;
    long b = id / LAT;
    const float* xr = h2 + b * (long)(C2 * HORIZON);

    float acc[HORIZON];
#pragma unroll
    for (int l = 0; l < HORIZON; l++) acc[l] = b3[co];

    for (int ci = 0; ci < C2; ci++) {
        float sc = bn2[ci * 2], sh = bn2[ci * 2 + 1];
        float xv[HORIZON];
#pragma unroll
        for (int tt = 0; tt < HORIZON; tt++) {
            float h = fmaf(xr[tt * C2 + ci], sc, sh);
            xv[tt] = h > 0.f ? h : expm1f(h);
        }
        float wv[HORIZON];
#pragma unroll
        for (int k = 0; k < HORIZON; k++) wv[k] = w3t[(ci * HORIZON + k) * LAT + co];
#pragma unroll
        for (int tt = 0; tt < HORIZON; tt++) {
            const int lo = (tt - PAD) > 0 ? (tt - PAD) : 0;
            const int hi = (tt + PAD) < (HORIZON - 1) ? (tt + PAD) : (HORIZON - 1);
#pragma unroll
            for (int l = lo; l <= hi; l++)
                acc[l] = fmaf(xv[tt], wv[tt - l + PAD], acc[l]);
        }
    }

    float ssum = 0.f;
#pragma unroll
    for (int l = 0; l < HORIZON; l++) ssum += acc[l];
    float b_off = ssum * (1.f / 15.f);

    float psum = 0.f, fnum = 0.f;
#pragma unroll
    for (int j = 0; j < 7; j++) {
        float re = 0.f, im = 0.f;
#pragma unroll
        for (int l = 0; l < HORIZON; l++) {
            float c = trig[(j * HORIZON + l) * 2];
            float s = trig[(j * HORIZON + l) * 2 + 1];
            re = fmaf(acc[l], c, re);
            im = fmaf(acc[l], s, im);
        }
        float p = fmaf(re, re, im * im);
        psum += p;
        fnum = fmaf((float)(j + 1), p, fnum);
    }
    float f = fnum / psum;
    float a = 2.f * sqrtf(psum) * (1.f / 15.f);

    float* orow = out + b * 24;
    orow[6 + co]  = f;
    orow[12 + co] = a;
    orow[18 + co] = b_off;

    float v0 = 0.f, v1 = 0.f;
#pragma unroll
    for (int l = 0; l < HORIZON; l++) {
        v0 = fmaf(acc[l], pw[(co * 2 + 0) * HORIZON + l], v0);
        v1 = fmaf(acc[l], pw[(co * 2 + 1) * HORIZON + l], v1);
    }
    vout[b * 12 + co * 2]     = v0;
    vout[b * 12 + co * 2 + 1] = v1;
    atomicAdd(&s_sum[co * 2], v0);
    atomicAdd(&s_sq[co * 2], v0 * v0);
    atomicAdd(&s_sum[co * 2 + 1], v1);
    atomicAdd(&s_sq[co * 2 + 1], v1 * v1);

    __syncthreads();
    float* st = stats + (blockIdx.x & (NREP - 1)) * 2 * (2 * LAT);
    if (t < 2 * LAT) {
        atomicAdd(&st[t], s_sum[t]);
        atomicAdd(&st[2 * LAT + t], s_sq[t]);
    }
}

// ---------------------------------------------------------------------------
__global__ void phase_kernel(const float* __restrict__ v, const float* __restrict__ bnP,
                             float* __restrict__ out, long B) {
    long b = (long)blockIdx.x * 256 + threadIdx.x;
    if (b >= B) return;
#pragma unroll
    for (int co = 0; co < LAT; co++) {
        float v0 = v[b * 12 + co * 2];
        float v1 = v[b * 12 + co * 2 + 1];
        int c0 = co * 2, c1 = co * 2 + 1;
        v0 = fmaf(v0, bnP[c0 * 2], bnP[c0 * 2 + 1]);
        v1 = fmaf(v1, bnP[c1 * 2], bnP[c1 * 2 + 1]);
        out[b * 24 + co] = atan2f(v1, v0) * 0.15915494309189535f;
    }
}

// ---------------------------------------------------------------------------
extern "C" void kernel_launch(void* const* d_in, const int* in_sizes, int n_in,
                              void* d_out, int out_size, void* d_ws, size_t ws_size,
                              hipStream_t stream) {
    const float* x   = (const float*)d_in[0];
    const float* w1  = (const float*)d_in[1];
    const float* g1  = (const float*)d_in[3];
    const float* be1 = (const float*)d_in[4];
    const float* w2  = (const float*)d_in[5];
    const float* g2  = (const float*)d_in[7];
    const float* be2 = (const float*)d_in[8];
    const float* w3  = (const float*)d_in[9];
    const float* b3  = (const float*)d_in[10];
    const float* pw  = (const float*)d_in[11];
    const float* pg  = (const float*)d_in[13];
    const float* pbe = (const float*)d_in[14];
    float* out = (float*)d_out;

    long B = (long)in_sizes[0] / (CIN * HORIZON);   // 65536

    // bf16 arrays FIRST: 16B-aligned base + 1472B row stride (16B-divisible).
    ushortT* w1h = (ushortT*)d_ws;          // 768*736
    ushortT* w1l = w1h + 768 * 736;
    ushortT* w2h = w1l + 768 * 736;         // 192*736
    ushortT* w2l = w2h + 192 * 736;
    float* y1 = (float*)(w2l + 192 * 736);  // 16B-aligned
    float* y2 = y1 + B * 720;               // B*180
    float* vv = y2 + B * 180;               // B*12
    float* stats1 = vv + B * 12;            // NREP*96
    float* stats2 = stats1 + NREP * 96;     // NREP*24
    float* statsP = stats2 + NREP * 24;     // NREP*24
    float* bn1 = statsP + NREP * 24;        // 96
    float* bn2 = bn1 + 96;                  // 24
    float* bnP = bn2 + 24;                  // 24
    float* w3t = bnP + 24;                  // 1080
    float* trig = w3t + C2 * HORIZON * LAT; // 210

    hipMemsetAsync(stats1, 0, NREP * (96 + 24 + 24) * sizeof(float), stream);

    const int prep_total = 768 * 736 + 192 * 736 + C2 * HORIZON * LAT + 7 * HORIZON;
    prep_kernel<<<(prep_total + 255) / 256, 256, 0, stream>>>(w1, w2, w3, w1h, w1l, w2h, w2l, w3t, trig);

    // GEMM1: x [B][720] -> y1 [B][720], stats1
    // grid.x = col-groups (adjacent blocks share the A slab -> L2 reuse)
    gemm_split<15, 48, false><<<dim3(3, (int)(B / 128)), 256, 0, stream>>>(
        x, 720, w1h, w1l, nullptr, y1, 720, 720, stats1);
    finalize_bn<<<1, 64, 0, stream>>>(stats1, g1, be1, bn1, CIN, 1.f / (float)(B * HORIZON));

    // GEMM2: BN1+ELU fused in A-staging; y1 -> y2 [B][180], stats2
    gemm_split<12, 12, true><<<dim3(1, (int)(B / 128)), 256, 0, stream>>>(
        y1, 720, w2h, w2l, bn1, y2, 180, 180, stats2);
    finalize_bn<<<1, 64, 0, stream>>>(stats2, g2, be2, bn2, C2, 1.f / (float)(B * HORIZON));

    // tail: BN2+ELU fused on load
    tail_kernel<<<(int)(B * LAT / 256), 256, 0, stream>>>(y2, w3t, b3, pw, trig, bn2, out, vv, statsP);
    finalize_bn<<<1, 64, 0, stream>>>(statsP, pg, pbe, bnP, 2 * LAT, 1.f / (float)B);

    phase_kernel<<<(int)((B + 255) / 256), 256, 0, stream>>>(vv, bnP, out, B);
}